// Round 1
// baseline (2208.032 us; speedup 1.0000x reference)
//
#include <hip/hip_runtime.h>

#define DIM 64

// ---------------------------------------------------------------------------
// deg[v] = number of occurrences of v in the flat adj_t array (both rows),
// which equals segment_sum(ones, col) of the doubled (undirected) edge list.
// ---------------------------------------------------------------------------
__global__ void count_deg_kernel(const int* __restrict__ adj, int total,
                                 int* __restrict__ deg) {
    int i = blockIdx.x * blockDim.x + threadIdx.x;
    if (i < total) atomicAdd(&deg[adj[i]], 1);
}

__global__ void dinv_kernel(const int* __restrict__ deg,
                            float* __restrict__ dinv, int n) {
    int i = blockIdx.x * blockDim.x + threadIdx.x;
    if (i < n) {
        int d = deg[i];
        dinv[i] = (d > 0) ? rsqrtf((float)d) : 0.0f;
    }
}

// w_e = dinv[a] * dinv[b] — symmetric, shared by both directed copies.
__global__ void weight_kernel(const int* __restrict__ adj, int E,
                              const float* __restrict__ dinv,
                              float* __restrict__ w) {
    int e = blockIdx.x * blockDim.x + threadIdx.x;
    if (e < E) w[e] = dinv[adj[e]] * dinv[adj[E + e]];
}

// out = 0.25 * x   (full overwrite — d_out is poisoned before timed launches)
__global__ void scale_init_kernel(const float4* __restrict__ x,
                                  float4* __restrict__ out, int n4) {
    int i = blockIdx.x * blockDim.x + threadIdx.x;
    if (i < n4) {
        float4 v = x[i];
        out[i] = make_float4(0.25f * v.x, 0.25f * v.y, 0.25f * v.z, 0.25f * v.w);
    }
}

// One 64-lane wave per ORIGINAL edge; lane = feature dim.
// y[b][lane] += w * x[a][lane];  y[a][lane] += w * x[b][lane];
__global__ void spmm_kernel(const int* __restrict__ adj, int E,
                            const float* __restrict__ w,
                            const float* __restrict__ xin,
                            float* __restrict__ y) {
    int t = blockIdx.x * blockDim.x + threadIdx.x;
    int e = t >> 6;
    int lane = t & 63;
    if (e >= E) return;
    int a = adj[e];
    int b = adj[E + e];
    float we = w[e];
    float va = xin[(size_t)a * DIM + lane];
    float vb = xin[(size_t)b * DIM + lane];
    atomicAdd(&y[(size_t)b * DIM + lane], we * va);
    atomicAdd(&y[(size_t)a * DIM + lane], we * vb);
}

// out += 0.25 * y
__global__ void axpy_kernel(const float4* __restrict__ y,
                            float4* __restrict__ out, int n4) {
    int i = blockIdx.x * blockDim.x + threadIdx.x;
    if (i < n4) {
        float4 v = y[i];
        float4 o = out[i];
        o.x += 0.25f * v.x;
        o.y += 0.25f * v.y;
        o.z += 0.25f * v.z;
        o.w += 0.25f * v.w;
        out[i] = o;
    }
}

extern "C" void kernel_launch(void* const* d_in, const int* in_sizes, int n_in,
                              void* d_out, int out_size, void* d_ws, size_t ws_size,
                              hipStream_t stream) {
    const float* x  = (const float*)d_in[0];
    const int* adj  = (const int*)d_in[1];   // harness delivers integer inputs as int32
    float* out      = (float*)d_out;

    const int total_adj = in_sizes[1];       // 2*E entries
    const int E = total_adj / 2;
    const int N = in_sizes[0] / DIM;
    const size_t nfeat = (size_t)N * DIM;

    // Workspace layout (all offsets 256-aligned):
    //   [0,      0.5MB) deg      (N ints,   400 KB)
    //   [0.5MB,  1.0MB) dinv     (N floats, 400 KB)
    //   [1MB,    8MB  ) w        (E floats, 6.4 MB)
    //   [8MB,    34MB ) xA       (N*64 floats, 25.6 MB)
    //   [34MB,   60MB ) xB       (N*64 floats, 25.6 MB)
    char* ws   = (char*)d_ws;
    int*   deg  = (int*)  (ws);
    float* dinv = (float*)(ws + (size_t)512 * 1024);
    float* w    = (float*)(ws + (size_t)1024 * 1024);
    float* xA   = (float*)(ws + (size_t)8 * 1024 * 1024);
    float* xB   = (float*)(ws + (size_t)34 * 1024 * 1024);

    const int B = 256;

    // 1) degrees
    hipMemsetAsync(deg, 0, (size_t)N * sizeof(int), stream);
    count_deg_kernel<<<(total_adj + B - 1) / B, B, 0, stream>>>(adj, total_adj, deg);

    // 2) dinv
    dinv_kernel<<<(N + B - 1) / B, B, 0, stream>>>(deg, dinv, N);

    // 3) per-edge weights
    weight_kernel<<<(E + B - 1) / B, B, 0, stream>>>(adj, E, dinv, w);

    // 4) out = 0.25 * x0
    const int n4 = (int)(nfeat / 4);
    scale_init_kernel<<<(n4 + B - 1) / B, B, 0, stream>>>(
        (const float4*)x, (float4*)out, n4);

    // 5) three propagation layers, ping-pong xA/xB
    const float* xin = x;
    float* bufs[2] = {xA, xB};
    for (int l = 0; l < 3; ++l) {
        float* y = bufs[l & 1];
        hipMemsetAsync(y, 0, nfeat * sizeof(float), stream);
        long long threads = (long long)E * 64;
        int blocks = (int)((threads + B - 1) / B);
        spmm_kernel<<<blocks, B, 0, stream>>>(adj, E, w, xin, y);
        axpy_kernel<<<(n4 + B - 1) / B, B, 0, stream>>>(
            (const float4*)y, (float4*)out, n4);
        xin = y;
    }
}

// Round 2
// 776.286 us; speedup vs baseline: 2.8444x; 2.8444x over previous
//
#include <hip/hip_runtime.h>

#define DIM 64
#define SCAN_B 256

// ---------------------------------------------------------------------------
// deg[v] = occurrences of v anywhere in adj (= in-degree of doubled edge list)
// ---------------------------------------------------------------------------
__global__ void count_deg_kernel(const int* __restrict__ adj, int total,
                                 int* __restrict__ deg) {
    int i = blockIdx.x * blockDim.x + threadIdx.x;
    if (i < total) atomicAdd(&deg[adj[i]], 1);
}

__global__ void dinv_kernel(const int* __restrict__ deg,
                            float* __restrict__ dinv, int n) {
    int i = blockIdx.x * blockDim.x + threadIdx.x;
    if (i < n) {
        int d = deg[i];
        dinv[i] = (d > 0) ? rsqrtf((float)d) : 0.0f;
    }
}

// --------------------------- prefix scan (3 stages) ------------------------
__global__ void scan_block_kernel(const int* __restrict__ deg, int n,
                                  int* __restrict__ row_ptr,
                                  int* __restrict__ blocksums) {
    __shared__ int tmp[SCAN_B];
    int i = blockIdx.x * SCAN_B + threadIdx.x;
    int v = (i < n) ? deg[i] : 0;
    tmp[threadIdx.x] = v;
    __syncthreads();
    for (int off = 1; off < SCAN_B; off <<= 1) {
        int t = (threadIdx.x >= off) ? tmp[threadIdx.x - off] : 0;
        __syncthreads();
        tmp[threadIdx.x] += t;
        __syncthreads();
    }
    if (i < n) row_ptr[i] = tmp[threadIdx.x] - v;       // exclusive
    if (threadIdx.x == SCAN_B - 1) blocksums[blockIdx.x] = tmp[SCAN_B - 1];
}

__global__ void scan_sums_kernel(int* __restrict__ blocksums, int nb) {
    __shared__ int tmp[512];
    int v = (threadIdx.x < nb) ? blocksums[threadIdx.x] : 0;
    tmp[threadIdx.x] = v;
    __syncthreads();
    for (int off = 1; off < 512; off <<= 1) {
        int t = (threadIdx.x >= off) ? tmp[threadIdx.x - off] : 0;
        __syncthreads();
        tmp[threadIdx.x] += t;
        __syncthreads();
    }
    if (threadIdx.x < nb) blocksums[threadIdx.x] = tmp[threadIdx.x] - v;  // exclusive
}

__global__ void scan_add_kernel(int* __restrict__ row_ptr,
                                const int* __restrict__ blocksums,
                                int n, int total_edges) {
    int i = blockIdx.x * blockDim.x + threadIdx.x;
    if (i < n) row_ptr[i] += blocksums[i / SCAN_B];
    if (i == n) row_ptr[n] = total_edges;
}

// ------------------------------ CSR scatter --------------------------------
// For each original edge (a,b): add a to b's list and b to a's list.
__global__ void scatter_csr_kernel(const int* __restrict__ adj, int E,
                                   const int* __restrict__ row_ptr,
                                   int* __restrict__ cursor,
                                   int* __restrict__ csr_src) {
    int e = blockIdx.x * blockDim.x + threadIdx.x;
    if (e >= E) return;
    int a = adj[e];
    int b = adj[E + e];
    int p1 = row_ptr[b] + atomicAdd(&cursor[b], 1);
    csr_src[p1] = a;
    int p2 = row_ptr[a] + atomicAdd(&cursor[a], 1);
    csr_src[p2] = b;
}

// ------------------------------- init --------------------------------------
// out = 0.25*x ; xs = dinv ⊙ x     (float4: 4 consecutive dims of one node)
__global__ void init_kernel(const float4* __restrict__ x,
                            const float* __restrict__ dinv,
                            float4* __restrict__ out,
                            float4* __restrict__ xs, int n4) {
    int i = blockIdx.x * blockDim.x + threadIdx.x;
    if (i >= n4) return;
    float4 v = x[i];
    out[i] = make_float4(0.25f * v.x, 0.25f * v.y, 0.25f * v.z, 0.25f * v.w);
    float di = dinv[i >> 4];   // 16 float4 per node
    xs[i] = make_float4(di * v.x, di * v.y, di * v.z, di * v.w);
}

// ------------------------------- SpMM --------------------------------------
// One wave per node, lane = dim.
//   acc    = Σ_{u∈N(v)} xs_in[u]
//   y      = dinv[v] * acc          (true layer output)
//   out   += 0.25 * y
//   xs_out = dinv[v] * y
__global__ void spmm_csr_kernel(const int* __restrict__ row_ptr,
                                const int* __restrict__ csr_src,
                                const float* __restrict__ dinv,
                                const float* __restrict__ xs_in,
                                float* __restrict__ xs_out,
                                float* __restrict__ out, int N) {
    int v = (blockIdx.x * blockDim.x + threadIdx.x) >> 6;
    int lane = threadIdx.x & 63;
    if (v >= N) return;
    int beg = row_ptr[v];
    int end = row_ptr[v + 1];
    float acc = 0.0f;
    int j = beg;
    for (; j + 4 <= end; j += 4) {
        int s0 = csr_src[j];
        int s1 = csr_src[j + 1];
        int s2 = csr_src[j + 2];
        int s3 = csr_src[j + 3];
        float a0 = xs_in[(size_t)s0 * DIM + lane];
        float a1 = xs_in[(size_t)s1 * DIM + lane];
        float a2 = xs_in[(size_t)s2 * DIM + lane];
        float a3 = xs_in[(size_t)s3 * DIM + lane];
        acc += a0 + a1 + a2 + a3;
    }
    for (; j < end; ++j) acc += xs_in[(size_t)csr_src[j] * DIM + lane];
    float di = dinv[v];
    float y = di * acc;
    size_t o = (size_t)v * DIM + lane;
    out[o] += 0.25f * y;
    xs_out[o] = di * y;
}

extern "C" void kernel_launch(void* const* d_in, const int* in_sizes, int n_in,
                              void* d_out, int out_size, void* d_ws, size_t ws_size,
                              hipStream_t stream) {
    const float* x = (const float*)d_in[0];
    const int* adj = (const int*)d_in[1];
    float* out     = (float*)d_out;

    const int total_adj = in_sizes[1];   // 2*E
    const int E = total_adj / 2;
    const int N = in_sizes[0] / DIM;
    const size_t nfeat = (size_t)N * DIM;

    // Workspace layout:
    //   [0.0MB, 0.5MB)  deg (later reused as cursor)   N ints
    //   [0.5MB, 1.0MB)  dinv                            N floats
    //   [1.0MB, 1.4MB)  row_ptr                         N+1 ints
    //   [1.45MB,1.5MB)  blocksums                       ≤512 ints
    //   [1.5MB, 14.5MB) csr_src                         2E ints (12.8MB)
    //   [14.5MB,40.5MB) xsA                             25.6MB
    //   [40.5MB,66.5MB) xsB                             25.6MB
    char* ws = (char*)d_ws;
    int*   deg       = (int*)(ws);
    float* dinv      = (float*)(ws + (size_t)512 * 1024);
    int*   row_ptr   = (int*)(ws + (size_t)1024 * 1024);
    int*   blocksums = (int*)(ws + (size_t)1485 * 1024);
    int*   csr_src   = (int*)(ws + (size_t)1536 * 1024);
    float* xsA       = (float*)(ws + (size_t)14848 * 1024);   // 14.5MB
    float* xsB       = (float*)(ws + (size_t)41472 * 1024);   // 40.5MB

    const int B = 256;
    const int nscan = (N + SCAN_B - 1) / SCAN_B;

    // 1) degrees
    hipMemsetAsync(deg, 0, (size_t)N * sizeof(int), stream);
    count_deg_kernel<<<(total_adj + B - 1) / B, B, 0, stream>>>(adj, total_adj, deg);

    // 2) dinv
    dinv_kernel<<<(N + B - 1) / B, B, 0, stream>>>(deg, dinv, N);

    // 3) row_ptr = exclusive_scan(deg)
    scan_block_kernel<<<nscan, SCAN_B, 0, stream>>>(deg, N, row_ptr, blocksums);
    scan_sums_kernel<<<1, 512, 0, stream>>>(blocksums, nscan);
    scan_add_kernel<<<(N + 1 + B - 1) / B, B, 0, stream>>>(row_ptr, blocksums, N, total_adj);

    // 4) CSR scatter (deg reused as cursor)
    hipMemsetAsync(deg, 0, (size_t)N * sizeof(int), stream);
    scatter_csr_kernel<<<(E + B - 1) / B, B, 0, stream>>>(adj, E, row_ptr, deg, csr_src);

    // 5) out = 0.25*x0 ; xsA = dinv ⊙ x0
    const int n4 = (int)(nfeat / 4);
    init_kernel<<<(n4 + B - 1) / B, B, 0, stream>>>(
        (const float4*)x, dinv, (float4*)out, (float4*)xsA, n4);

    // 6) three fused propagation layers
    const long long threads = (long long)N * 64;
    const int blocks = (int)((threads + B - 1) / B);
    float* xin = xsA;
    float* xout = xsB;
    for (int l = 0; l < 3; ++l) {
        spmm_csr_kernel<<<blocks, B, 0, stream>>>(row_ptr, csr_src, dinv,
                                                  xin, xout, out, N);
        float* t = xin; xin = xout; xout = t;
    }
}